// Round 9
// baseline (1394.697 us; speedup 1.0000x reference)
//
#include <hip/hip_runtime.h>

#define B_   1024
#define TE   168
#define TD   24
#define F_   64
#define H_   128
#define H2_  256
#define G_   512

// ---- workspace float offsets ----
#define OFF_WhT    0          // dec Wh pair-packed [128 pairs][2*128] (32768 halfs)
#define OFF_dWihT  16384      // dec dWih pair-packed (65536 halfs)
#define OFF_dWhhT  49152      // dec dWhh pair-packed (65536 halfs)
#define OFF_ENCB   81920
#define OFF_MIDB   82432
#define OFF_DECB   82944
#define OFF_W16    83456      // fp16 row-major weight block (half offsets below)
#define W16_We     0          // [128][256]
#define W16_Wi     32768      // [128][64]
#define W16_Vd     40960      // [64][128]
#define W16_eWih   49152      // [512][64]
#define W16_eWhh   81920      // [512][128]
#define W16_mWih   147456     // [512][128]
#define W16_mWhh   212992     // [512][128]
#define W16_Wx     278528     // [128][128]
#define W16_TOT    294912     // halfs
#define OFF_MID    230912                         // half [1024][168][128]: h_enc, overwritten in-place by midH
#define OFF_WX     (OFF_MID + (B_*TE*H_)/2)       // half [1024][168][128]
#define OFF_STH    (OFF_WX  + (B_*TE*H_)/2)
#define OFF_STC    (OFF_STH + B_*H_)
#define WS_FLOATS  (OFF_STC + B_*H_)

typedef _Float16 h2 __attribute__((ext_vector_type(2)));
typedef _Float16 h8 __attribute__((ext_vector_type(8)));
typedef _Float16 f16x8 __attribute__((ext_vector_type(8)));
typedef float    f32x4 __attribute__((ext_vector_type(4)));

__device__ __forceinline__ float fexp2(float x) { return __builtin_amdgcn_exp2f(x); }
__device__ __forceinline__ float frcp(float x)  { return __builtin_amdgcn_rcpf(x); }
#define LOG2E 1.4426950408889634f

__device__ __forceinline__ float sigm(float x) {
    return frcp(1.f + fexp2(-LOG2E * x));
}
__device__ __forceinline__ float tanh_fast(float x) {
    float e = fexp2(2.f * LOG2E * x);
    return 1.f - 2.f * frcp(e + 1.f);
}

__device__ __forceinline__ float fdot2(h2 a, h2 b, float c) {
#if __has_builtin(__builtin_amdgcn_fdot2)
    return __builtin_amdgcn_fdot2(a, b, c, false);
#else
    return c + (float)a[0] * (float)b[0] + (float)a[1] * (float)b[1];
#endif
}
__device__ __forceinline__ void fma4(float4& g, const float4 wv, const float s) {
    g.x = __builtin_fmaf(wv.x, s, g.x);
    g.y = __builtin_fmaf(wv.y, s, g.y);
    g.z = __builtin_fmaf(wv.z, s, g.z);
    g.w = __builtin_fmaf(wv.w, s, g.w);
}

#define SH(V,I)  __builtin_shufflevector(V, V, 2*(I), 2*(I)+1)
#define SL(CG)   (4*((CG) + ((CG)>>3)))   // bank-optimal lane->slot swizzle (decoder)

// 2-row dot-pair variant (decoder only)
#define DPAIR2(LOV, HIV, R0, R1) { \
    h2 c0=SH(LOV,0), c1=SH(LOV,1), c2=SH(LOV,2), c3=SH(LOV,3); \
    h2 c4=SH(HIV,0), c5=SH(HIV,1), c6=SH(HIV,2), c7=SH(HIV,3); \
    a00.x=fdot2(R0,c0,a00.x); a00.y=fdot2(R0,c1,a00.y); a00.z=fdot2(R0,c2,a00.z); a00.w=fdot2(R0,c3,a00.w); \
    a01.x=fdot2(R0,c4,a01.x); a01.y=fdot2(R0,c5,a01.y); a01.z=fdot2(R0,c6,a01.z); a01.w=fdot2(R0,c7,a01.w); \
    a10.x=fdot2(R1,c0,a10.x); a10.y=fdot2(R1,c1,a10.y); a10.z=fdot2(R1,c2,a10.z); a10.w=fdot2(R1,c3,a10.w); \
    a11.x=fdot2(R1,c4,a11.x); a11.y=fdot2(R1,c5,a11.y); a11.z=fdot2(R1,c6,a11.z); a11.w=fdot2(R1,c7,a11.w); \
}

__device__ __forceinline__ f32x4 mfma16(f16x8 a, f16x8 b, f32x4 c) {
    return __builtin_amdgcn_mfma_f32_16x16x32_f16(a, b, c, 0, 0, 0);
}

// ---------------- prep: pair-packed dec weights + biases + fp16 copies + flag zero ----------------
struct PrepArgs {
    const float *We, *Wi, *Vd, *eWih, *eWhh, *eBih, *eBhh,
                *mWih, *mWhh, *mBih, *mBhh, *Wx, *Wh, *dWih, *dWhh, *dBih, *dBhh;
};

__global__ void prep_kernel(PrepArgs a, float* __restrict__ ws, int* __restrict__ flags) {
    int sec  = blockIdx.x >> 2;
    int base = (blockIdx.x & 3) * blockDim.x + threadIdx.x;
    const int stride = blockDim.x * 4;
    _Float16* w16 = (_Float16*)(ws + OFF_W16);

    if (sec <= 2) {
        // pack pairs for decoder: dst[(c>>1)*2R + 2r + (c&1)] = src[r*C + c]
        const float* src = (sec == 0) ? a.Wh : (sec == 1) ? a.dWih : a.dWhh;
        int R = (sec == 0) ? 128 : 512;
        int C = (sec == 0) ? 256 : 128;
        int off = (sec == 0) ? OFF_WhT : (sec == 1) ? OFF_dWihT : OFF_dWhhT;
        int n = R * C;
        _Float16* hd = (_Float16*)(ws + off);
        for (int o = base; o < n; o += stride) {
            int r = o % R, c = o / R;
            hd[(c >> 1) * 2 * R + 2 * r + (c & 1)] = (_Float16)src[r * C + c];
        }
    } else if (sec == 3) {
        for (int i = base; i < 512; i += stride) ws[OFF_ENCB + i] = a.eBih[i] + a.eBhh[i];
    } else if (sec == 4) {
        for (int i = base; i < 512; i += stride) ws[OFF_MIDB + i] = a.mBih[i] + a.mBhh[i];
    } else if (sec == 5) {
        for (int i = base; i < 512; i += stride) ws[OFF_DECB + i] = a.dBih[i] + a.dBhh[i];
        for (int i = base; i < 64; i += stride) flags[i] = 0;   // pipeline flags (in d_out)
    } else if (sec <= 13) {
        const int dsto[8] = {W16_We, W16_Wi, W16_Vd, W16_eWih, W16_eWhh, W16_mWih, W16_mWhh, W16_Wx};
        const int cnt[8]  = {32768, 8192, 8192, 32768, 65536, 65536, 65536, 16384};
        const float* srcs[8] = {a.We, a.Wi, a.Vd, a.eWih, a.eWhh, a.mWih, a.mWhh, a.Wx};
        int k = sec - 6;
        const float* s = srcs[k];
        _Float16* d = w16 + dsto[k];
        int n = cnt[k];
        for (int i = base; i < n; i += stride) d[i] = (_Float16)s[i];
    }
}

// ---------------- fused enc+mid pipeline: 128 blocks x 512 thr ----------------
// blocks 0-63: encoder (16 rows each, 3 barriers/t); blocks 64-127: mid LSTM trailing by <=8 t
__global__ __launch_bounds__(512, 1) void enc_mid_kernel(
    const float* __restrict__ x_all,
    const float* __restrict__ Wi_b,
    const float* __restrict__ Vd_b,
    const float* __restrict__ Wx_b,
    float* __restrict__ ws,
    int* __restrict__ flags)
{
    const int tid  = threadIdx.x;
    const int wave = tid >> 6;
    const int lane = tid & 63;
    const int g    = lane >> 4;
    const int cc   = lane & 15;
    const int role = blockIdx.x >> 6;       // 0 = enc, 1 = mid
    const int grp  = blockIdx.x & 63;
    const int b0   = grp * 16;
    const int col  = wave * 16 + cc;
    const _Float16* w16 = (const _Float16*)(ws + OFF_W16);
    _Float16* hencG = (_Float16*)(ws + OFF_MID);

    if (role == 0) {
        // ================= ENCODER ROLE =================
        __shared__ __align__(16) _Float16 m1In[16][328];      // [h|c|x]
        __shared__ __align__(16) _Float16 encIn[2][16][200];  // dbuf: [xin(0:64)|h(64:192)]
        __shared__ __align__(16) _Float16 avT[16][136];
        __shared__ __align__(16) float xf[16][64];
        __shared__ __align__(16) float cE[16][132];
        __shared__ float bWi[H_], bVd[F_], bE[G_];

        for (int i = tid; i < 16 * 328; i += 512) ((_Float16*)m1In)[i]  = (_Float16)0.f;
        for (int i = tid; i < 2 * 16 * 200; i += 512) ((_Float16*)encIn)[i] = (_Float16)0.f;
        for (int i = tid; i < 16 * 132; i += 512) ((float*)cE)[i] = 0.f;
        if (tid < H_) bWi[tid] = Wi_b[tid];
        if (tid < F_) bVd[tid] = Vd_b[tid];
        bE[tid] = ws[OFF_ENCB + tid];
        if (tid < 256) {
            int m = tid >> 4, c4 = (tid & 15) * 4;
            float4 v = *(const float4*)&x_all[((size_t)(b0 + m) * TE + 0) * F_ + c4];
            *(float4*)&xf[m][c4] = v;
            m1In[m][256 + c4]     = (_Float16)v.x;
            m1In[m][256 + c4 + 1] = (_Float16)v.y;
            m1In[m][256 + c4 + 2] = (_Float16)v.z;
            m1In[m][256 + c4 + 3] = (_Float16)v.w;
        }

        f16x8 wWe[8], wWi[2], wVd[4][4], wIh[4][2], wHh[4][4];
        {
            const _Float16* p = w16 + W16_We + (size_t)col * 256 + 8 * g;
            #pragma unroll
            for (int ks = 0; ks < 8; ++ks) wWe[ks] = *(const f16x8*)(p + ks * 32);
            const _Float16* p2 = w16 + W16_Wi + (size_t)col * 64 + 8 * g;
            wWi[0] = *(const f16x8*)(p2);
            wWi[1] = *(const f16x8*)(p2 + 32);
            if (wave < 4) {   // all 4 Vd n-tiles (redundant-compute softmax)
                #pragma unroll
                for (int nt = 0; nt < 4; ++nt) {
                    const _Float16* p3 = w16 + W16_Vd + (size_t)(nt * 16 + cc) * 128 + 8 * g;
                    #pragma unroll
                    for (int ks = 0; ks < 4; ++ks) wVd[nt][ks] = *(const f16x8*)(p3 + ks * 32);
                }
            } else {
                #pragma unroll
                for (int nt = 0; nt < 4; ++nt)
                    #pragma unroll
                    for (int ks = 0; ks < 4; ++ks) wVd[nt][ks] = f16x8{};
            }
            #pragma unroll
            for (int q = 0; q < 4; ++q) {
                const _Float16* pi = w16 + W16_eWih + (size_t)(q * 128 + col) * 64 + 8 * g;
                wIh[q][0] = *(const f16x8*)(pi);
                wIh[q][1] = *(const f16x8*)(pi + 32);
                const _Float16* ph = w16 + W16_eWhh + (size_t)(q * 128 + col) * 128 + 8 * g;
                #pragma unroll
                for (int ks = 0; ks < 4; ++ks) wHh[q][ks] = *(const f16x8*)(ph + ks * 32);
            }
        }
        __syncthreads();

        float4 xr = make_float4(0.f, 0.f, 0.f, 0.f);

        for (int t = 0; t < TE; ++t) {
            const int buf = t & 1;
            // ---- P1: m1 = [h|c|x] @ [We|Wi]^T -> av
            {
                f16x8 aF[10];
                #pragma unroll
                for (int ks = 0; ks < 10; ++ks)
                    aF[ks] = *(const f16x8*)&m1In[cc][ks * 32 + 8 * g];
                f32x4 acc = {0.f, 0.f, 0.f, 0.f};
                #pragma unroll
                for (int ks = 0; ks < 8; ++ks)
                    acc = mfma16(aF[ks], wWe[ks], acc);
                acc = mfma16(aF[8], wWi[0], acc);
                acc = mfma16(aF[9], wWi[1], acc);
                float bw = bWi[col];
                #pragma unroll
                for (int r = 0; r < 4; ++r)
                    avT[4 * g + r][col] = (_Float16)tanh_fast(acc[r] + bw);
            }
            __syncthreads();   // barrier A

            // ---- P2m: s = av @ Vd^T (ALL 4 n-tiles, waves 0-3) + in-wave softmax -> xin
            if (wave < 4) {
                f16x8 aF[4];
                #pragma unroll
                for (int ks = 0; ks < 4; ++ks)
                    aF[ks] = *(const f16x8*)&avT[cc][ks * 32 + 8 * g];
                f32x4 sA0 = {0.f,0.f,0.f,0.f}, sA1 = sA0, sA2 = sA0, sA3 = sA0;
                #pragma unroll
                for (int ks = 0; ks < 4; ++ks) {
                    sA0 = mfma16(aF[ks], wVd[0][ks], sA0);
                    sA1 = mfma16(aF[ks], wVd[1][ks], sA1);
                    sA2 = mfma16(aF[ks], wVd[2][ks], sA2);
                    sA3 = mfma16(aF[ks], wVd[3][ks], sA3);
                }
                float bv0 = bVd[cc], bv1 = bVd[16 + cc], bv2 = bVd[32 + cc], bv3 = bVd[48 + cc];
                #pragma unroll
                for (int r = 0; r < 4; ++r) {
                    float s0 = sA0[r] + bv0, s1 = sA1[r] + bv1, s2 = sA2[r] + bv2, s3 = sA3[r] + bv3;
                    float mx = fmaxf(fmaxf(s0, s1), fmaxf(s2, s3));
                    #pragma unroll
                    for (int off = 8; off > 0; off >>= 1) mx = fmaxf(mx, __shfl_xor(mx, off, 16));
                    float e0 = fexp2((s0 - mx) * LOG2E), e1 = fexp2((s1 - mx) * LOG2E);
                    float e2 = fexp2((s2 - mx) * LOG2E), e3 = fexp2((s3 - mx) * LOG2E);
                    float sm = (e0 + e1) + (e2 + e3);
                    #pragma unroll
                    for (int off = 8; off > 0; off >>= 1) sm += __shfl_xor(sm, off, 16);
                    float rs = frcp(sm);
                    float ew = (wave == 0) ? e0 : (wave == 1) ? e1 : (wave == 2) ? e2 : e3;
                    int m = 4 * g + r;
                    encIn[buf][m][col] = (_Float16)(xf[m][col] * ew * rs);
                }
            } else if (t + 1 < TE) {
                int q = tid - 256, m = q >> 4, c4 = (q & 15) * 4;
                xr = *(const float4*)&x_all[((size_t)(b0 + m) * TE + (t + 1)) * F_ + c4];
            }
            __syncthreads();   // barrier B

            // ---- P4: enc gates from encIn[buf]; ep writes h into encIn[buf^1] (no barrier between)
            f32x4 ge[4];
            {
                f16x8 aF[6];
                #pragma unroll
                for (int ks = 0; ks < 6; ++ks)
                    aF[ks] = *(const f16x8*)&encIn[buf][cc][ks * 32 + 8 * g];
                #pragma unroll
                for (int q = 0; q < 4; ++q) {
                    f32x4 acc = {0.f, 0.f, 0.f, 0.f};
                    acc = mfma16(aF[0], wIh[q][0], acc);
                    acc = mfma16(aF[1], wIh[q][1], acc);
                    #pragma unroll
                    for (int ks = 0; ks < 4; ++ks)
                        acc = mfma16(aF[2 + ks], wHh[q][ks], acc);
                    ge[q] = acc;
                }
            }
            // ---- ep: LSTM cell + h_enc store + x install (writes only buf^1 / m1In — no WAR)
            {
                float bi = bE[col], bf = bE[col + 128], bg = bE[col + 256], bo = bE[col + 384];
                #pragma unroll
                for (int r = 0; r < 4; ++r) {
                    int m = 4 * g + r;
                    float gi = ge[0][r] + bi, gf = ge[1][r] + bf,
                          gg = ge[2][r] + bg, go = ge[3][r] + bo;
                    float cn = sigm(gf) * cE[m][col] + sigm(gi) * tanh_fast(gg);
                    float h  = sigm(go) * tanh_fast(cn);
                    cE[m][col] = cn;
                    _Float16 hh = (_Float16)h;
                    encIn[buf ^ 1][m][64 + col] = hh;
                    m1In[m][col]       = hh;
                    m1In[m][128 + col] = (_Float16)cn;
                    hencG[((size_t)(b0 + m) * TE + t) * H_ + col] = hh;
                }
                if (tid >= 256 && t + 1 < TE) {
                    int q = tid - 256, m = q >> 4, c4 = (q & 15) * 4;
                    *(float4*)&xf[m][c4] = xr;
                    m1In[m][256 + c4]     = (_Float16)xr.x;
                    m1In[m][256 + c4 + 1] = (_Float16)xr.y;
                    m1In[m][256 + c4 + 2] = (_Float16)xr.z;
                    m1In[m][256 + c4 + 3] = (_Float16)xr.w;
                }
            }
            __syncthreads();   // barrier C (drains h_enc stores before publish)
            if (((t + 1) & 7) == 0 && tid == 0)
                __hip_atomic_store(flags + grp, t + 1, __ATOMIC_RELEASE, __HIP_MEMORY_SCOPE_AGENT);
        }
    } else {
        // ================= MID ROLE (trails enc by <=8 t; unchanged) =================
        __shared__ __align__(16) _Float16 midIn[16][264];
        __shared__ __align__(16) float cM[16][132];
        __shared__ float bM[G_], bWx[H_];

        for (int i = tid; i < 16 * 264; i += 512) ((_Float16*)midIn)[i] = (_Float16)0.f;
        for (int i = tid; i < 16 * 132; i += 512) ((float*)cM)[i] = 0.f;
        if (tid < H_) bWx[tid] = Wx_b[tid];
        bM[tid] = ws[OFF_MIDB + tid];

        f16x8 wIhB[4][4], wHhB[4][4], wWx[4];
        {
            #pragma unroll
            for (int q = 0; q < 4; ++q) {
                const _Float16* pi = w16 + W16_mWih + (size_t)(q * 128 + col) * 128 + 8 * g;
                const _Float16* ph = w16 + W16_mWhh + (size_t)(q * 128 + col) * 128 + 8 * g;
                #pragma unroll
                for (int ks = 0; ks < 4; ++ks) {
                    wIhB[q][ks] = *(const f16x8*)(pi + ks * 32);
                    wHhB[q][ks] = *(const f16x8*)(ph + ks * 32);
                }
            }
            const _Float16* px = w16 + W16_Wx + (size_t)col * 128 + 8 * g;
            #pragma unroll
            for (int ks = 0; ks < 4; ++ks) wWx[ks] = *(const f16x8*)(px + ks * 32);
        }
        _Float16* wxH = (_Float16*)(ws + OFF_WX);
        __syncthreads();

        // wait for first enc burst (t=0..7), install h_enc(0)
        if (tid == 0) {
            while (__hip_atomic_load(flags + grp, __ATOMIC_ACQUIRE, __HIP_MEMORY_SCOPE_AGENT) < 8)
                __builtin_amdgcn_s_sleep(4);
        }
        __syncthreads();
        if (tid < 256) {
            int m = tid >> 4, s8 = (tid & 15) * 8;
            *(f16x8*)&midIn[m][s8] = *(const f16x8*)&hencG[((size_t)(b0 + m) * TE + 0) * H_ + s8];
        }
        __syncthreads();

        f16x8 hpre = {};
        f32x4 accx = {0.f, 0.f, 0.f, 0.f};

        for (int t = 0; t < TE; ++t) {
            const bool pre_ok = (t + 1 < TE) && (((t + 1) & 7) != 0);
            f32x4 gm[4];
            {
                f16x8 aF[8];
                #pragma unroll
                for (int ks = 0; ks < 8; ++ks)
                    aF[ks] = *(const f16x8*)&midIn[cc][ks * 32 + 8 * g];
                #pragma unroll
                for (int q = 0; q < 4; ++q) {
                    f32x4 acc = {0.f, 0.f, 0.f, 0.f};
                    #pragma unroll
                    for (int ks = 0; ks < 4; ++ks)
                        acc = mfma16(aF[ks], wIhB[q][ks], acc);
                    #pragma unroll
                    for (int ks = 0; ks < 4; ++ks)
                        acc = mfma16(aF[4 + ks], wHhB[q][ks], acc);
                    gm[q] = acc;
                }
                if (t > 0) {
                    f32x4 acc = {0.f, 0.f, 0.f, 0.f};
                    #pragma unroll
                    for (int ks = 0; ks < 4; ++ks)
                        acc = mfma16(aF[4 + ks], wWx[ks], acc);
                    accx = acc;
                }
            }
            if (tid < 256 && pre_ok) {
                int m = tid >> 4, s8 = (tid & 15) * 8;
                hpre = *(const f16x8*)&hencG[((size_t)(b0 + m) * TE + (t + 1)) * H_ + s8];
            }
            __syncthreads();

            {
                float bi = bM[col], bf = bM[col + 128], bg = bM[col + 256], bo = bM[col + 384];
                float bw = bWx[col];
                #pragma unroll
                for (int r = 0; r < 4; ++r) {
                    int m = 4 * g + r;
                    float gi = gm[0][r] + bi, gf = gm[1][r] + bf,
                          gg = gm[2][r] + bg, go = gm[3][r] + bo;
                    float cn = sigm(gf) * cM[m][col] + sigm(gi) * tanh_fast(gg);
                    float h  = sigm(go) * tanh_fast(cn);
                    cM[m][col] = cn;
                    _Float16 hh = (_Float16)h;
                    midIn[m][128 + col] = hh;
                    hencG[((size_t)(b0 + m) * TE + t) * H_ + col] = hh;
                    if (t > 0)
                        wxH[((size_t)(b0 + m) * TE + (t - 1)) * H_ + col] = (_Float16)(accx[r] + bw);
                }
                if (tid < 256 && pre_ok) {
                    int m = tid >> 4, s8 = (tid & 15) * 8;
                    *(f16x8*)&midIn[m][s8] = hpre;
                }
            }
            __syncthreads();

            if (t + 1 < TE && ((t + 1) & 7) == 0) {
                if (tid == 0) {
                    while (__hip_atomic_load(flags + grp, __ATOMIC_ACQUIRE, __HIP_MEMORY_SCOPE_AGENT) < t + 9)
                        __builtin_amdgcn_s_sleep(4);
                }
                __syncthreads();
                if (tid < 256) {
                    int m = tid >> 4, s8 = (tid & 15) * 8;
                    *(f16x8*)&midIn[m][s8] = *(const f16x8*)&hencG[((size_t)(b0 + m) * TE + (t + 1)) * H_ + s8];
                }
                __syncthreads();
            }
        }

        // final wx(TE-1)
        {
            f16x8 ax[4];
            #pragma unroll
            for (int ks = 0; ks < 4; ++ks)
                ax[ks] = *(const f16x8*)&midIn[cc][128 + ks * 32 + 8 * g];
            f32x4 acc = {0.f, 0.f, 0.f, 0.f};
            #pragma unroll
            for (int ks = 0; ks < 4; ++ks)
                acc = mfma16(ax[ks], wWx[ks], acc);
            float bw = bWx[col];
            #pragma unroll
            for (int r = 0; r < 4; ++r) {
                int m = 4 * g + r;
                wxH[((size_t)(b0 + m) * TE + (TE - 1)) * H_ + col] = (_Float16)(acc[r] + bw);
            }
        }
        for (int idx = tid; idx < 2048; idx += 512) {
            int m = idx >> 7, j = idx & 127;
            ws[OFF_STH + (b0 + m) * H_ + j] = (float)midIn[m][128 + j];
            ws[OFF_STC + (b0 + m) * H_ + j] = cM[m][j];
        }
    }
}

// ---------------- decoder (round-2 proven config): 512 blocks x 512 thr, 2 rows/block ----------------
#define QP_ 132

__global__ __launch_bounds__(512, 2) void dec_kernel(
    const float* __restrict__ Vw_in,
    const float* __restrict__ Vb_in,
    const float* __restrict__ rw_in,
    const float* __restrict__ rb_in,
    const float* __restrict__ ws,
    float* __restrict__ out)
{
    __shared__ __align__(16) float scr[9216];        // 36KB partials
    __shared__ __align__(16) float hc2[2][H2_];
    __shared__ __align__(16) float qv[2][QP_];
    __shared__ __align__(16) float sb[2][TE];
    __shared__ __align__(16) float dinp[8][2][H_];
    __shared__ float bD[G_], Vw[H_], rw[H_];

    const int tid = threadIdx.x;
    const int b0  = blockIdx.x * 2;
    const float Vb = Vb_in[0], rb = rb_in[0];

    {
        int r = tid >> 8, c = tid & 255;
        hc2[r][c] = (c < H_) ? ws[OFF_STH + (b0 + r) * H_ + c]
                             : ws[OFF_STC + (b0 + r) * H_ + (c - H_)];
    }
    if (tid < H_) { Vw[tid] = Vw_in[tid]; rw[tid] = rw_in[tid]; }
    bD[tid] = ws[OFF_DECB + tid];
    __syncthreads();

    const h8* WhH2  = (const h8*)(ws + OFF_WhT);     // [128 pairs][32]
    const h8* dWih2 = (const h8*)(ws + OFF_dWihT);   // [64 pairs][128]
    const h8* dWhh2 = (const h8*)(ws + OFF_dWhhT);   // [64 pairs][128]
    const h8* wx8   = (const h8*)(ws + OFF_WX);
    typedef _Float16 h4 __attribute__((ext_vector_type(4)));
    const h4* mid4 = (const h4*)(ws + OFF_MID);

    for (int td = 0; td < TD; ++td) {
        // P1: q partials = [hi|ci]@WhT  (cg16 x 8cols, ks32, 4 pairs each, both rows)
        {
            int cg = tid & 15, ks = tid >> 4;
            int p0 = ks * 4;
            float4 a00 = make_float4(0.f,0.f,0.f,0.f), a01 = a00, a10 = a00, a11 = a00;
            #pragma unroll
            for (int i = 0; i < 4; ++i) {
                int p = p0 + i;
                h8 lo = WhH2[p * 32 + cg * 2];
                h8 hi = WhH2[p * 32 + cg * 2 + 1];
                h2 r0; r0[0] = (_Float16)hc2[0][2*p]; r0[1] = (_Float16)hc2[0][2*p+1];
                h2 r1; r1[0] = (_Float16)hc2[1][2*p]; r1[1] = (_Float16)hc2[1][2*p+1];
                DPAIR2(lo, hi, r0, r1);
            }
            int sl = SL(cg);
            float* sp = scr + ks * 288;
            *(float4*)(sp +       sl) = a00; *(float4*)(sp +  72 + sl) = a01;
            *(float4*)(sp + 144 + sl) = a10; *(float4*)(sp + 216 + sl) = a11;
        }
        __syncthreads();
        // P1b: combine 32
        if (tid < 256) {
            int j = tid & 127, r = tid >> 7;
            int e = j & 7, cgj = j >> 3;
            int idx = r * 144 + ((e < 4) ? SL(cgj) + e : 72 + SL(cgj) + (e - 4));
            float v = 0.f;
            #pragma unroll
            for (int ks = 0; ks < 32; ++ks) v += scr[ks * 288 + idx];
            qv[r][j] = v;
        }
        __syncthreads();

        // P2: scores (round-2 full-width form)
        for (int task = tid; task < 2 * TE; task += 512) {
            int r = (task >= TE) ? 1 : 0;
            int tp = task - r * TE;
            const h8* wxr = wx8 + ((size_t)(b0 + r) * TE + tp) * 16;
            float acc = Vb;
            #pragma unroll 4
            for (int kk = 0; kk < 16; ++kk) {
                h8 hv = wxr[kk];
                int j = kk * 8;
                float4 q0 = *(const float4*)&qv[r][j], q1 = *(const float4*)&qv[r][j + 4];
                float4 v0 = *(const float4*)&Vw[j],    v1 = *(const float4*)&Vw[j + 4];
                acc += tanh_fast(q0.x + (float)hv[0]) * v0.x + tanh_fast(q0.y + (float)hv[1]) * v0.y
                     + tanh_fast(q0.z + (float)hv[2]) * v0.z + tanh_fast(q0.w + (float)hv[3]) * v0.w;
                acc += tanh_fast(q1.x + (float)hv[4]) * v1.x + tanh_fast(q1.y + (float)hv[5]) * v1.y
                     + tanh_fast(q1.z + (float)hv[6]) * v1.z + tanh_fast(q1.w + (float)hv[7]) * v1.w;
            }
            sb[r][tp] = acc;
        }
        __syncthreads();

        // P3: dec_in partials over tp chunks of 21
        {
            int ts = tid >> 6, r = (tid >> 5) & 1, cg = tid & 31;
            int t0 = ts * 21;
            float4 a = make_float4(0.f, 0.f, 0.f, 0.f);
            #pragma unroll 3
            for (int tp = t0; tp < t0 + 21; ++tp) {
                float s = sb[r][tp];
                h4 m = mid4[((size_t)(b0 + r) * TE + tp) * 32 + cg];
                float4 mf;
                mf.x = (float)m[0]; mf.y = (float)m[1]; mf.z = (float)m[2]; mf.w = (float)m[3];
                fma4(a, mf, s);
            }
            *(float4*)&dinp[ts][r][cg * 4] = a;
        }
        __syncthreads();
        // P3b: combine into qv (dec_in)
        if (tid < 256) {
            int j = tid & 127, r = tid >> 7;
            qv[r][j] = ((dinp[0][r][j] + dinp[1][r][j]) + (dinp[2][r][j] + dinp[3][r][j]))
                     + ((dinp[4][r][j] + dinp[5][r][j]) + (dinp[6][r][j] + dinp[7][r][j]));
        }
        __syncthreads();

        // P4: gate partials = dec_in@dWih + hi@dWhh  (cg64, ks8, 8+8 pairs)
        {
            int cg = tid & 63, ks = tid >> 6;
            int p0 = ks * 8;
            float4 a00 = make_float4(0.f,0.f,0.f,0.f), a01 = a00, a10 = a00, a11 = a00;
            #pragma unroll 4
            for (int i = 0; i < 8; ++i) {
                int p = p0 + i;
                h8 lo = dWih2[p * 128 + cg * 2];
                h8 hi = dWih2[p * 128 + cg * 2 + 1];
                h2 r0; r0[0] = (_Float16)qv[0][2*p]; r0[1] = (_Float16)qv[0][2*p+1];
                h2 r1; r1[0] = (_Float16)qv[1][2*p]; r1[1] = (_Float16)qv[1][2*p+1];
                DPAIR2(lo, hi, r0, r1);
            }
            #pragma unroll 4
            for (int i = 0; i < 8; ++i) {
                int p = p0 + i;
                h8 lo = dWhh2[p * 128 + cg * 2];
                h8 hi = dWhh2[p * 128 + cg * 2 + 1];
                h2 r0; r0[0] = (_Float16)hc2[0][2*p]; r0[1] = (_Float16)hc2[0][2*p+1];
                h2 r1; r1[0] = (_Float16)hc2[1][2*p]; r1[1] = (_Float16)hc2[1][2*p+1];
                DPAIR2(lo, hi, r0, r1);
            }
            int sl = SL(cg);
            float* sp = scr + ks * 1152;
            *(float4*)(sp +       sl) = a00; *(float4*)(sp + 288 + sl) = a01;
            *(float4*)(sp + 576 + sl) = a10; *(float4*)(sp + 864 + sl) = a11;
        }
        __syncthreads();

        // P5: combine 8 + LSTM update
        if (tid < 256) {
            int j = tid & 127, r = tid >> 7;
            int e = j & 7, cgj = j >> 3;
            int i0, i1, i2, i3;
            {
                int c0 = cgj, c1 = 16 + cgj, c2 = 32 + cgj, c3 = 48 + cgj;
                i0 = (e < 4) ? SL(c0) + e : 288 + SL(c0) + (e - 4);
                i1 = (e < 4) ? SL(c1) + e : 288 + SL(c1) + (e - 4);
                i2 = (e < 4) ? SL(c2) + e : 288 + SL(c2) + (e - 4);
                i3 = (e < 4) ? SL(c3) + e : 288 + SL(c3) + (e - 4);
            }
            const float* sp = scr + r * 576;
            float gi = bD[j], gf = bD[j + 128], gg = bD[j + 256], go = bD[j + 384];
            #pragma unroll
            for (int ks = 0; ks < 8; ++ks) {
                const float* p = sp + ks * 1152;
                gi += p[i0]; gf += p[i1]; gg += p[i2]; go += p[i3];
            }
            float c = sigm(gf) * hc2[r][H_ + j] + sigm(gi) * tanh_fast(gg);
            float h = sigm(go) * tanh_fast(c);
            hc2[r][H_ + j] = c; hc2[r][j] = h;
        }
        __syncthreads();

        // P6: output dot (no trailing barrier needed)
        if (tid < 128) {
            int r = tid >> 6, lane = tid & 63;
            float v = hc2[r][lane] * rw[lane] + hc2[r][lane + 64] * rw[lane + 64];
            for (int off = 32; off > 0; off >>= 1) v += __shfl_xor(v, off, 64);
            if (lane == 0) out[(b0 + r) * TD + td] = v + rb;
        }
    }
}

extern "C" void kernel_launch(void* const* d_in, const int* in_sizes, int n_in,
                              void* d_out, int out_size, void* d_ws, size_t ws_size,
                              hipStream_t stream)
{
    (void)in_sizes; (void)n_in; (void)out_size;
    if (ws_size < (size_t)WS_FLOATS * sizeof(float)) return;

    const float* x_all = (const float*)d_in[0];
    const float* Wi_b  = (const float*)d_in[3];
    const float* Vd_b  = (const float*)d_in[6];
    const float* Wx_b  = (const float*)d_in[16];
    const float* V_w   = (const float*)d_in[18];
    const float* V_b   = (const float*)d_in[19];
    const float* reg_w = (const float*)d_in[24];
    const float* reg_b = (const float*)d_in[25];
    float* ws  = (float*)d_ws;
    float* out = (float*)d_out;
    int* flags = (int*)d_out;   // first 64 ints of out; zeroed by prep, overwritten by dec

    PrepArgs pa{
        (const float*)d_in[4],  // We_w
        (const float*)d_in[2],  // Wi_w
        (const float*)d_in[5],  // Vd_w
        (const float*)d_in[7],  // enc_Wih
        (const float*)d_in[8],  // enc_Whh
        (const float*)d_in[9],  // enc_bih
        (const float*)d_in[10], // enc_bhh
        (const float*)d_in[11], // mid_Wih
        (const float*)d_in[12], // mid_Whh
        (const float*)d_in[13], // mid_bih
        (const float*)d_in[14], // mid_bhh
        (const float*)d_in[15], // Wx_w
        (const float*)d_in[17], // Wh_w
        (const float*)d_in[20], // dec_Wih
        (const float*)d_in[21], // dec_Whh
        (const float*)d_in[22], // dec_bih
        (const float*)d_in[23]  // dec_bhh
    };

    prep_kernel<<<56, 256, 0, stream>>>(pa, ws, flags);
    enc_mid_kernel<<<128, 512, 0, stream>>>(x_all, Wi_b, Vd_b, Wx_b, ws, flags);
    dec_kernel<<<512, 512, 0, stream>>>(V_w, V_b, reg_w, reg_b, ws, out);
}

// Round 10
// 1066.515 us; speedup vs baseline: 1.3077x; 1.3077x over previous
//
#include <hip/hip_runtime.h>

#define B_   1024
#define TE   168
#define TD   24
#define F_   64
#define H_   128
#define H2_  256
#define G_   512

// ---- workspace float offsets ----
#define OFF_WhT    0          // dec Wh pair-packed [128 pairs][2*128] (32768 halfs)
#define OFF_dWihT  16384      // dec dWih pair-packed (65536 halfs)
#define OFF_dWhhT  49152      // dec dWhh pair-packed (65536 halfs)
#define OFF_ENCB   81920
#define OFF_MIDB   82432
#define OFF_DECB   82944
#define OFF_W16    83456      // fp16 row-major weight block (half offsets below)
#define W16_We     0          // [128][256]
#define W16_Wi     32768      // [128][64]
#define W16_Vd     40960      // [64][128]
#define W16_eWih   49152      // [512][64]
#define W16_eWhh   81920      // [512][128]
#define W16_mWih   147456     // [512][128]
#define W16_mWhh   212992     // [512][128]
#define W16_Wx     278528     // [128][128]
#define W16_TOT    294912     // halfs
#define OFF_MID    230912                         // half [1024][168][128]: h_enc, overwritten in-place by midH
#define OFF_WX     (OFF_MID + (B_*TE*H_)/2)       // half [1024][168][128]
#define OFF_STH    (OFF_WX  + (B_*TE*H_)/2)
#define OFF_STC    (OFF_STH + B_*H_)
#define WS_FLOATS  (OFF_STC + B_*H_)

typedef _Float16 h2 __attribute__((ext_vector_type(2)));
typedef _Float16 h8 __attribute__((ext_vector_type(8)));
typedef _Float16 f16x8 __attribute__((ext_vector_type(8)));
typedef float    f32x4 __attribute__((ext_vector_type(4)));

__device__ __forceinline__ float fexp2(float x) { return __builtin_amdgcn_exp2f(x); }
__device__ __forceinline__ float frcp(float x)  { return __builtin_amdgcn_rcpf(x); }
#define LOG2E 1.4426950408889634f

__device__ __forceinline__ float sigm(float x) {
    return frcp(1.f + fexp2(-LOG2E * x));
}
__device__ __forceinline__ float tanh_fast(float x) {
    float e = fexp2(2.f * LOG2E * x);
    return 1.f - 2.f * frcp(e + 1.f);
}

__device__ __forceinline__ float fdot2(h2 a, h2 b, float c) {
#if __has_builtin(__builtin_amdgcn_fdot2)
    return __builtin_amdgcn_fdot2(a, b, c, false);
#else
    return c + (float)a[0] * (float)b[0] + (float)a[1] * (float)b[1];
#endif
}
__device__ __forceinline__ void fma4(float4& g, const float4 wv, const float s) {
    g.x = __builtin_fmaf(wv.x, s, g.x);
    g.y = __builtin_fmaf(wv.y, s, g.y);
    g.z = __builtin_fmaf(wv.z, s, g.z);
    g.w = __builtin_fmaf(wv.w, s, g.w);
}

#define SH(V,I)  __builtin_shufflevector(V, V, 2*(I), 2*(I)+1)
#define SL(CG)   (4*((CG) + ((CG)>>3)))   // bank-optimal lane->slot swizzle (decoder)

// 2-row dot-pair variant (decoder only)
#define DPAIR2(LOV, HIV, R0, R1) { \
    h2 c0=SH(LOV,0), c1=SH(LOV,1), c2=SH(LOV,2), c3=SH(LOV,3); \
    h2 c4=SH(HIV,0), c5=SH(HIV,1), c6=SH(HIV,2), c7=SH(HIV,3); \
    a00.x=fdot2(R0,c0,a00.x); a00.y=fdot2(R0,c1,a00.y); a00.z=fdot2(R0,c2,a00.z); a00.w=fdot2(R0,c3,a00.w); \
    a01.x=fdot2(R0,c4,a01.x); a01.y=fdot2(R0,c5,a01.y); a01.z=fdot2(R0,c6,a01.z); a01.w=fdot2(R0,c7,a01.w); \
    a10.x=fdot2(R1,c0,a10.x); a10.y=fdot2(R1,c1,a10.y); a10.z=fdot2(R1,c2,a10.z); a10.w=fdot2(R1,c3,a10.w); \
    a11.x=fdot2(R1,c4,a11.x); a11.y=fdot2(R1,c5,a11.y); a11.z=fdot2(R1,c6,a11.z); a11.w=fdot2(R1,c7,a11.w); \
}

__device__ __forceinline__ f32x4 mfma16(f16x8 a, f16x8 b, f32x4 c) {
    return __builtin_amdgcn_mfma_f32_16x16x32_f16(a, b, c, 0, 0, 0);
}

// ---------------- prep: pair-packed dec weights + biases + fp16 copies + flag zero ----------------
struct PrepArgs {
    const float *We, *Wi, *Vd, *eWih, *eWhh, *eBih, *eBhh,
                *mWih, *mWhh, *mBih, *mBhh, *Wx, *Wh, *dWih, *dWhh, *dBih, *dBhh;
};

__global__ void prep_kernel(PrepArgs a, float* __restrict__ ws, int* __restrict__ flags) {
    int sec  = blockIdx.x >> 2;
    int base = (blockIdx.x & 3) * blockDim.x + threadIdx.x;
    const int stride = blockDim.x * 4;
    _Float16* w16 = (_Float16*)(ws + OFF_W16);

    if (sec <= 2) {
        // pack pairs for decoder: dst[(c>>1)*2R + 2r + (c&1)] = src[r*C + c]
        const float* src = (sec == 0) ? a.Wh : (sec == 1) ? a.dWih : a.dWhh;
        int R = (sec == 0) ? 128 : 512;
        int C = (sec == 0) ? 256 : 128;
        int off = (sec == 0) ? OFF_WhT : (sec == 1) ? OFF_dWihT : OFF_dWhhT;
        int n = R * C;
        _Float16* hd = (_Float16*)(ws + off);
        for (int o = base; o < n; o += stride) {
            int r = o % R, c = o / R;
            hd[(c >> 1) * 2 * R + 2 * r + (c & 1)] = (_Float16)src[r * C + c];
        }
    } else if (sec == 3) {
        for (int i = base; i < 512; i += stride) ws[OFF_ENCB + i] = a.eBih[i] + a.eBhh[i];
    } else if (sec == 4) {
        for (int i = base; i < 512; i += stride) ws[OFF_MIDB + i] = a.mBih[i] + a.mBhh[i];
    } else if (sec == 5) {
        for (int i = base; i < 512; i += stride) ws[OFF_DECB + i] = a.dBih[i] + a.dBhh[i];
        for (int i = base; i < 64; i += stride) flags[i] = 0;   // pipeline flags (in d_out)
    } else if (sec <= 13) {
        const int dsto[8] = {W16_We, W16_Wi, W16_Vd, W16_eWih, W16_eWhh, W16_mWih, W16_mWhh, W16_Wx};
        const int cnt[8]  = {32768, 8192, 8192, 32768, 65536, 65536, 65536, 16384};
        const float* srcs[8] = {a.We, a.Wi, a.Vd, a.eWih, a.eWhh, a.mWih, a.mWhh, a.Wx};
        int k = sec - 6;
        const float* s = srcs[k];
        _Float16* d = w16 + dsto[k];
        int n = cnt[k];
        for (int i = base; i < n; i += stride) d[i] = (_Float16)s[i];
    }
}

// ---------------- fused enc+mid pipeline: 128 blocks x 512 thr ----------------
// blocks 0-63: encoder (16 rows each, 4 barriers/t via encIn dbuf); blocks 64-127: mid trailing <=8 t
__global__ __launch_bounds__(512, 1) void enc_mid_kernel(
    const float* __restrict__ x_all,
    const float* __restrict__ Wi_b,
    const float* __restrict__ Vd_b,
    const float* __restrict__ Wx_b,
    float* __restrict__ ws,
    int* __restrict__ flags)
{
    const int tid  = threadIdx.x;
    const int wave = tid >> 6;
    const int lane = tid & 63;
    const int g    = lane >> 4;
    const int cc   = lane & 15;
    const int role = blockIdx.x >> 6;       // 0 = enc, 1 = mid
    const int grp  = blockIdx.x & 63;
    const int b0   = grp * 16;
    const int col  = wave * 16 + cc;
    const _Float16* w16 = (const _Float16*)(ws + OFF_W16);
    _Float16* hencG = (_Float16*)(ws + OFF_MID);

    if (role == 0) {
        // ================= ENCODER ROLE =================
        __shared__ __align__(16) _Float16 m1In[16][328];      // [h|c|x]
        __shared__ __align__(16) _Float16 encIn[2][16][200];  // dbuf: [xin(0:64)|h(64:192)]
        __shared__ __align__(16) _Float16 avT[16][136];
        __shared__ __align__(16) float sS[16][68];
        __shared__ __align__(16) float xf[16][64];
        __shared__ __align__(16) float cE[16][132];
        __shared__ float bWi[H_], bVd[F_], bE[G_];

        for (int i = tid; i < 16 * 328; i += 512) ((_Float16*)m1In)[i]  = (_Float16)0.f;
        for (int i = tid; i < 2 * 16 * 200; i += 512) ((_Float16*)encIn)[i] = (_Float16)0.f;
        for (int i = tid; i < 16 * 132; i += 512) ((float*)cE)[i] = 0.f;
        if (tid < H_) bWi[tid] = Wi_b[tid];
        if (tid < F_) bVd[tid] = Vd_b[tid];
        bE[tid] = ws[OFF_ENCB + tid];
        if (tid < 256) {
            int m = tid >> 4, c4 = (tid & 15) * 4;
            float4 v = *(const float4*)&x_all[((size_t)(b0 + m) * TE + 0) * F_ + c4];
            *(float4*)&xf[m][c4] = v;
            m1In[m][256 + c4]     = (_Float16)v.x;
            m1In[m][256 + c4 + 1] = (_Float16)v.y;
            m1In[m][256 + c4 + 2] = (_Float16)v.z;
            m1In[m][256 + c4 + 3] = (_Float16)v.w;
        }

        f16x8 wWe[8], wWi[2], wVd[4], wIh[4][2], wHh[4][4];
        {
            const _Float16* p = w16 + W16_We + (size_t)col * 256 + 8 * g;
            #pragma unroll
            for (int ks = 0; ks < 8; ++ks) wWe[ks] = *(const f16x8*)(p + ks * 32);
            const _Float16* p2 = w16 + W16_Wi + (size_t)col * 64 + 8 * g;
            wWi[0] = *(const f16x8*)(p2);
            wWi[1] = *(const f16x8*)(p2 + 32);
            if (wave < 4) {
                const _Float16* p3 = w16 + W16_Vd + (size_t)col * 128 + 8 * g;
                #pragma unroll
                for (int ks = 0; ks < 4; ++ks) wVd[ks] = *(const f16x8*)(p3 + ks * 32);
            } else {
                #pragma unroll
                for (int ks = 0; ks < 4; ++ks) wVd[ks] = f16x8{};
            }
            #pragma unroll
            for (int q = 0; q < 4; ++q) {
                const _Float16* pi = w16 + W16_eWih + (size_t)(q * 128 + col) * 64 + 8 * g;
                wIh[q][0] = *(const f16x8*)(pi);
                wIh[q][1] = *(const f16x8*)(pi + 32);
                const _Float16* ph = w16 + W16_eWhh + (size_t)(q * 128 + col) * 128 + 8 * g;
                #pragma unroll
                for (int ks = 0; ks < 4; ++ks) wHh[q][ks] = *(const f16x8*)(ph + ks * 32);
            }
        }
        __syncthreads();

        float4 xr = make_float4(0.f, 0.f, 0.f, 0.f);

        for (int t = 0; t < TE; ++t) {
            const int buf = t & 1;
            // ---- P1: m1 = [h|c|x] @ [We|Wi]^T -> av
            {
                f16x8 aF[10];
                #pragma unroll
                for (int ks = 0; ks < 10; ++ks)
                    aF[ks] = *(const f16x8*)&m1In[cc][ks * 32 + 8 * g];
                f32x4 acc = {0.f, 0.f, 0.f, 0.f};
                #pragma unroll
                for (int ks = 0; ks < 8; ++ks)
                    acc = mfma16(aF[ks], wWe[ks], acc);
                acc = mfma16(aF[8], wWi[0], acc);
                acc = mfma16(aF[9], wWi[1], acc);
                float bw = bWi[col];
                #pragma unroll
                for (int r = 0; r < 4; ++r)
                    avT[4 * g + r][col] = (_Float16)tanh_fast(acc[r] + bw);
            }
            __syncthreads();   // barrier A

            // ---- P2: s = av @ Vd^T (waves 0-3); waves 4-7 prefetch x_{t+1}
            if (wave < 4) {
                f16x8 aF[4];
                #pragma unroll
                for (int ks = 0; ks < 4; ++ks)
                    aF[ks] = *(const f16x8*)&avT[cc][ks * 32 + 8 * g];
                f32x4 acc = {0.f, 0.f, 0.f, 0.f};
                #pragma unroll
                for (int ks = 0; ks < 4; ++ks)
                    acc = mfma16(aF[ks], wVd[ks], acc);
                float bv = bVd[col];
                #pragma unroll
                for (int r = 0; r < 4; ++r)
                    sS[4 * g + r][col] = acc[r] + bv;
            } else if (t + 1 < TE) {
                int q = tid - 256, m = q >> 4, c4 = (q & 15) * 4;
                xr = *(const float4*)&x_all[((size_t)(b0 + m) * TE + (t + 1)) * F_ + c4];
            }
            __syncthreads();   // barrier B

            // ---- P2b: softmax over 64 + xin -> encIn[buf]
            {
                int m = tid >> 5, c = tid & 31;
                float v0 = sS[m][c], v1 = sS[m][c + 32];
                float mx = fmaxf(v0, v1);
                #pragma unroll
                for (int off = 16; off > 0; off >>= 1) mx = fmaxf(mx, __shfl_xor(mx, off, 64));
                float e0 = fexp2((v0 - mx) * LOG2E);
                float e1 = fexp2((v1 - mx) * LOG2E);
                float sm = e0 + e1;
                #pragma unroll
                for (int off = 16; off > 0; off >>= 1) sm += __shfl_xor(sm, off, 64);
                float rs = frcp(sm);
                encIn[buf][m][c]      = (_Float16)(xf[m][c]      * e0 * rs);
                encIn[buf][m][c + 32] = (_Float16)(xf[m][c + 32] * e1 * rs);
            }
            __syncthreads();   // barrier C

            // ---- P4: enc gates from encIn[buf]; ep writes h into encIn[buf^1] (no barrier between)
            f32x4 ge[4];
            {
                f16x8 aF[6];
                #pragma unroll
                for (int ks = 0; ks < 6; ++ks)
                    aF[ks] = *(const f16x8*)&encIn[buf][cc][ks * 32 + 8 * g];
                #pragma unroll
                for (int q = 0; q < 4; ++q) {
                    f32x4 acc = {0.f, 0.f, 0.f, 0.f};
                    acc = mfma16(aF[0], wIh[q][0], acc);
                    acc = mfma16(aF[1], wIh[q][1], acc);
                    #pragma unroll
                    for (int ks = 0; ks < 4; ++ks)
                        acc = mfma16(aF[2 + ks], wHh[q][ks], acc);
                    ge[q] = acc;
                }
            }
            // ---- ep: LSTM cell + h_enc store + x install (writes only buf^1 / m1In — no WAR)
            {
                float bi = bE[col], bf = bE[col + 128], bg = bE[col + 256], bo = bE[col + 384];
                #pragma unroll
                for (int r = 0; r < 4; ++r) {
                    int m = 4 * g + r;
                    float gi = ge[0][r] + bi, gf = ge[1][r] + bf,
                          gg = ge[2][r] + bg, go = ge[3][r] + bo;
                    float cn = sigm(gf) * cE[m][col] + sigm(gi) * tanh_fast(gg);
                    float h  = sigm(go) * tanh_fast(cn);
                    cE[m][col] = cn;
                    _Float16 hh = (_Float16)h;
                    encIn[buf ^ 1][m][64 + col] = hh;
                    m1In[m][col]       = hh;
                    m1In[m][128 + col] = (_Float16)cn;
                    hencG[((size_t)(b0 + m) * TE + t) * H_ + col] = hh;
                }
                if (tid >= 256 && t + 1 < TE) {
                    int q = tid - 256, m = q >> 4, c4 = (q & 15) * 4;
                    *(float4*)&xf[m][c4] = xr;
                    m1In[m][256 + c4]     = (_Float16)xr.x;
                    m1In[m][256 + c4 + 1] = (_Float16)xr.y;
                    m1In[m][256 + c4 + 2] = (_Float16)xr.z;
                    m1In[m][256 + c4 + 3] = (_Float16)xr.w;
                }
            }
            __syncthreads();   // barrier D (drains h_enc stores before publish; orders m1In for next P1)
            if (((t + 1) & 7) == 0 && tid == 0)
                __hip_atomic_store(flags + grp, t + 1, __ATOMIC_RELEASE, __HIP_MEMORY_SCOPE_AGENT);
        }
    } else {
        // ================= MID ROLE (trails enc by <=8 t; unchanged) =================
        __shared__ __align__(16) _Float16 midIn[16][264];
        __shared__ __align__(16) float cM[16][132];
        __shared__ float bM[G_], bWx[H_];

        for (int i = tid; i < 16 * 264; i += 512) ((_Float16*)midIn)[i] = (_Float16)0.f;
        for (int i = tid; i < 16 * 132; i += 512) ((float*)cM)[i] = 0.f;
        if (tid < H_) bWx[tid] = Wx_b[tid];
        bM[tid] = ws[OFF_MIDB + tid];

        f16x8 wIhB[4][4], wHhB[4][4], wWx[4];
        {
            #pragma unroll
            for (int q = 0; q < 4; ++q) {
                const _Float16* pi = w16 + W16_mWih + (size_t)(q * 128 + col) * 128 + 8 * g;
                const _Float16* ph = w16 + W16_mWhh + (size_t)(q * 128 + col) * 128 + 8 * g;
                #pragma unroll
                for (int ks = 0; ks < 4; ++ks) {
                    wIhB[q][ks] = *(const f16x8*)(pi + ks * 32);
                    wHhB[q][ks] = *(const f16x8*)(ph + ks * 32);
                }
            }
            const _Float16* px = w16 + W16_Wx + (size_t)col * 128 + 8 * g;
            #pragma unroll
            for (int ks = 0; ks < 4; ++ks) wWx[ks] = *(const f16x8*)(px + ks * 32);
        }
        _Float16* wxH = (_Float16*)(ws + OFF_WX);
        __syncthreads();

        // wait for first enc burst (t=0..7), install h_enc(0)
        if (tid == 0) {
            while (__hip_atomic_load(flags + grp, __ATOMIC_ACQUIRE, __HIP_MEMORY_SCOPE_AGENT) < 8)
                __builtin_amdgcn_s_sleep(4);
        }
        __syncthreads();
        if (tid < 256) {
            int m = tid >> 4, s8 = (tid & 15) * 8;
            *(f16x8*)&midIn[m][s8] = *(const f16x8*)&hencG[((size_t)(b0 + m) * TE + 0) * H_ + s8];
        }
        __syncthreads();

        f16x8 hpre = {};
        f32x4 accx = {0.f, 0.f, 0.f, 0.f};

        for (int t = 0; t < TE; ++t) {
            const bool pre_ok = (t + 1 < TE) && (((t + 1) & 7) != 0);
            f32x4 gm[4];
            {
                f16x8 aF[8];
                #pragma unroll
                for (int ks = 0; ks < 8; ++ks)
                    aF[ks] = *(const f16x8*)&midIn[cc][ks * 32 + 8 * g];
                #pragma unroll
                for (int q = 0; q < 4; ++q) {
                    f32x4 acc = {0.f, 0.f, 0.f, 0.f};
                    #pragma unroll
                    for (int ks = 0; ks < 4; ++ks)
                        acc = mfma16(aF[ks], wIhB[q][ks], acc);
                    #pragma unroll
                    for (int ks = 0; ks < 4; ++ks)
                        acc = mfma16(aF[4 + ks], wHhB[q][ks], acc);
                    gm[q] = acc;
                }
                if (t > 0) {
                    f32x4 acc = {0.f, 0.f, 0.f, 0.f};
                    #pragma unroll
                    for (int ks = 0; ks < 4; ++ks)
                        acc = mfma16(aF[4 + ks], wWx[ks], acc);
                    accx = acc;
                }
            }
            if (tid < 256 && pre_ok) {
                int m = tid >> 4, s8 = (tid & 15) * 8;
                hpre = *(const f16x8*)&hencG[((size_t)(b0 + m) * TE + (t + 1)) * H_ + s8];
            }
            __syncthreads();

            {
                float bi = bM[col], bf = bM[col + 128], bg = bM[col + 256], bo = bM[col + 384];
                float bw = bWx[col];
                #pragma unroll
                for (int r = 0; r < 4; ++r) {
                    int m = 4 * g + r;
                    float gi = gm[0][r] + bi, gf = gm[1][r] + bf,
                          gg = gm[2][r] + bg, go = gm[3][r] + bo;
                    float cn = sigm(gf) * cM[m][col] + sigm(gi) * tanh_fast(gg);
                    float h  = sigm(go) * tanh_fast(cn);
                    cM[m][col] = cn;
                    _Float16 hh = (_Float16)h;
                    midIn[m][128 + col] = hh;
                    hencG[((size_t)(b0 + m) * TE + t) * H_ + col] = hh;
                    if (t > 0)
                        wxH[((size_t)(b0 + m) * TE + (t - 1)) * H_ + col] = (_Float16)(accx[r] + bw);
                }
                if (tid < 256 && pre_ok) {
                    int m = tid >> 4, s8 = (tid & 15) * 8;
                    *(f16x8*)&midIn[m][s8] = hpre;
                }
            }
            __syncthreads();

            if (t + 1 < TE && ((t + 1) & 7) == 0) {
                if (tid == 0) {
                    while (__hip_atomic_load(flags + grp, __ATOMIC_ACQUIRE, __HIP_MEMORY_SCOPE_AGENT) < t + 9)
                        __builtin_amdgcn_s_sleep(4);
                }
                __syncthreads();
                if (tid < 256) {
                    int m = tid >> 4, s8 = (tid & 15) * 8;
                    *(f16x8*)&midIn[m][s8] = *(const f16x8*)&hencG[((size_t)(b0 + m) * TE + (t + 1)) * H_ + s8];
                }
                __syncthreads();
            }
        }

        // final wx(TE-1)
        {
            f16x8 ax[4];
            #pragma unroll
            for (int ks = 0; ks < 4; ++ks)
                ax[ks] = *(const f16x8*)&midIn[cc][128 + ks * 32 + 8 * g];
            f32x4 acc = {0.f, 0.f, 0.f, 0.f};
            #pragma unroll
            for (int ks = 0; ks < 4; ++ks)
                acc = mfma16(ax[ks], wWx[ks], acc);
            float bw = bWx[col];
            #pragma unroll
            for (int r = 0; r < 4; ++r) {
                int m = 4 * g + r;
                wxH[((size_t)(b0 + m) * TE + (TE - 1)) * H_ + col] = (_Float16)(acc[r] + bw);
            }
        }
        for (int idx = tid; idx < 2048; idx += 512) {
            int m = idx >> 7, j = idx & 127;
            ws[OFF_STH + (b0 + m) * H_ + j] = (float)midIn[m][128 + j];
            ws[OFF_STC + (b0 + m) * H_ + j] = cM[m][j];
        }
    }
}

// ---------------- decoder (round-2 proven config): 512 blocks x 512 thr, 2 rows/block ----------------
#define QP_ 132

__global__ __launch_bounds__(512, 2) void dec_kernel(
    const float* __restrict__ Vw_in,
    const float* __restrict__ Vb_in,
    const float* __restrict__ rw_in,
    const float* __restrict__ rb_in,
    const float* __restrict__ ws,
    float* __restrict__ out)
{
    __shared__ __align__(16) float scr[9216];        // 36KB partials
    __shared__ __align__(16) float hc2[2][H2_];
    __shared__ __align__(16) float qv[2][QP_];
    __shared__ __align__(16) float sb[2][TE];
    __shared__ __align__(16) float dinp[8][2][H_];
    __shared__ float bD[G_], Vw[H_], rw[H_];

    const int tid = threadIdx.x;
    const int b0  = blockIdx.x * 2;
    const float Vb = Vb_in[0], rb = rb_in[0];

    {
        int r = tid >> 8, c = tid & 255;
        hc2[r][c] = (c < H_) ? ws[OFF_STH + (b0 + r) * H_ + c]
                             : ws[OFF_STC + (b0 + r) * H_ + (c - H_)];
    }
    if (tid < H_) { Vw[tid] = Vw_in[tid]; rw[tid] = rw_in[tid]; }
    bD[tid] = ws[OFF_DECB + tid];
    __syncthreads();

    const h8* WhH2  = (const h8*)(ws + OFF_WhT);     // [128 pairs][32]
    const h8* dWih2 = (const h8*)(ws + OFF_dWihT);   // [64 pairs][128]
    const h8* dWhh2 = (const h8*)(ws + OFF_dWhhT);   // [64 pairs][128]
    const h8* wx8   = (const h8*)(ws + OFF_WX);
    typedef _Float16 h4 __attribute__((ext_vector_type(4)));
    const h4* mid4 = (const h4*)(ws + OFF_MID);

    for (int td = 0; td < TD; ++td) {
        // P1: q partials = [hi|ci]@WhT  (cg16 x 8cols, ks32, 4 pairs each, both rows)
        {
            int cg = tid & 15, ks = tid >> 4;
            int p0 = ks * 4;
            float4 a00 = make_float4(0.f,0.f,0.f,0.f), a01 = a00, a10 = a00, a11 = a00;
            #pragma unroll
            for (int i = 0; i < 4; ++i) {
                int p = p0 + i;
                h8 lo = WhH2[p * 32 + cg * 2];
                h8 hi = WhH2[p * 32 + cg * 2 + 1];
                h2 r0; r0[0] = (_Float16)hc2[0][2*p]; r0[1] = (_Float16)hc2[0][2*p+1];
                h2 r1; r1[0] = (_Float16)hc2[1][2*p]; r1[1] = (_Float16)hc2[1][2*p+1];
                DPAIR2(lo, hi, r0, r1);
            }
            int sl = SL(cg);
            float* sp = scr + ks * 288;
            *(float4*)(sp +       sl) = a00; *(float4*)(sp +  72 + sl) = a01;
            *(float4*)(sp + 144 + sl) = a10; *(float4*)(sp + 216 + sl) = a11;
        }
        __syncthreads();
        // P1b: combine 32
        if (tid < 256) {
            int j = tid & 127, r = tid >> 7;
            int e = j & 7, cgj = j >> 3;
            int idx = r * 144 + ((e < 4) ? SL(cgj) + e : 72 + SL(cgj) + (e - 4));
            float v = 0.f;
            #pragma unroll
            for (int ks = 0; ks < 32; ++ks) v += scr[ks * 288 + idx];
            qv[r][j] = v;
        }
        __syncthreads();

        // P2: scores (round-2 full-width form)
        for (int task = tid; task < 2 * TE; task += 512) {
            int r = (task >= TE) ? 1 : 0;
            int tp = task - r * TE;
            const h8* wxr = wx8 + ((size_t)(b0 + r) * TE + tp) * 16;
            float acc = Vb;
            #pragma unroll 4
            for (int kk = 0; kk < 16; ++kk) {
                h8 hv = wxr[kk];
                int j = kk * 8;
                float4 q0 = *(const float4*)&qv[r][j], q1 = *(const float4*)&qv[r][j + 4];
                float4 v0 = *(const float4*)&Vw[j],    v1 = *(const float4*)&Vw[j + 4];
                acc += tanh_fast(q0.x + (float)hv[0]) * v0.x + tanh_fast(q0.y + (float)hv[1]) * v0.y
                     + tanh_fast(q0.z + (float)hv[2]) * v0.z + tanh_fast(q0.w + (float)hv[3]) * v0.w;
                acc += tanh_fast(q1.x + (float)hv[4]) * v1.x + tanh_fast(q1.y + (float)hv[5]) * v1.y
                     + tanh_fast(q1.z + (float)hv[6]) * v1.z + tanh_fast(q1.w + (float)hv[7]) * v1.w;
            }
            sb[r][tp] = acc;
        }
        __syncthreads();

        // P3: dec_in partials over tp chunks of 21
        {
            int ts = tid >> 6, r = (tid >> 5) & 1, cg = tid & 31;
            int t0 = ts * 21;
            float4 a = make_float4(0.f, 0.f, 0.f, 0.f);
            #pragma unroll 3
            for (int tp = t0; tp < t0 + 21; ++tp) {
                float s = sb[r][tp];
                h4 m = mid4[((size_t)(b0 + r) * TE + tp) * 32 + cg];
                float4 mf;
                mf.x = (float)m[0]; mf.y = (float)m[1]; mf.z = (float)m[2]; mf.w = (float)m[3];
                fma4(a, mf, s);
            }
            *(float4*)&dinp[ts][r][cg * 4] = a;
        }
        __syncthreads();
        // P3b: combine into qv (dec_in)
        if (tid < 256) {
            int j = tid & 127, r = tid >> 7;
            qv[r][j] = ((dinp[0][r][j] + dinp[1][r][j]) + (dinp[2][r][j] + dinp[3][r][j]))
                     + ((dinp[4][r][j] + dinp[5][r][j]) + (dinp[6][r][j] + dinp[7][r][j]));
        }
        __syncthreads();

        // P4: gate partials = dec_in@dWih + hi@dWhh  (cg64, ks8, 8+8 pairs)
        {
            int cg = tid & 63, ks = tid >> 6;
            int p0 = ks * 8;
            float4 a00 = make_float4(0.f,0.f,0.f,0.f), a01 = a00, a10 = a00, a11 = a00;
            #pragma unroll 4
            for (int i = 0; i < 8; ++i) {
                int p = p0 + i;
                h8 lo = dWih2[p * 128 + cg * 2];
                h8 hi = dWih2[p * 128 + cg * 2 + 1];
                h2 r0; r0[0] = (_Float16)qv[0][2*p]; r0[1] = (_Float16)qv[0][2*p+1];
                h2 r1; r1[0] = (_Float16)qv[1][2*p]; r1[1] = (_Float16)qv[1][2*p+1];
                DPAIR2(lo, hi, r0, r1);
            }
            #pragma unroll 4
            for (int i = 0; i < 8; ++i) {
                int p = p0 + i;
                h8 lo = dWhh2[p * 128 + cg * 2];
                h8 hi = dWhh2[p * 128 + cg * 2 + 1];
                h2 r0; r0[0] = (_Float16)hc2[0][2*p]; r0[1] = (_Float16)hc2[0][2*p+1];
                h2 r1; r1[0] = (_Float16)hc2[1][2*p]; r1[1] = (_Float16)hc2[1][2*p+1];
                DPAIR2(lo, hi, r0, r1);
            }
            int sl = SL(cg);
            float* sp = scr + ks * 1152;
            *(float4*)(sp +       sl) = a00; *(float4*)(sp + 288 + sl) = a01;
            *(float4*)(sp + 576 + sl) = a10; *(float4*)(sp + 864 + sl) = a11;
        }
        __syncthreads();

        // P5: combine 8 + LSTM update
        if (tid < 256) {
            int j = tid & 127, r = tid >> 7;
            int e = j & 7, cgj = j >> 3;
            int i0, i1, i2, i3;
            {
                int c0 = cgj, c1 = 16 + cgj, c2 = 32 + cgj, c3 = 48 + cgj;
                i0 = (e < 4) ? SL(c0) + e : 288 + SL(c0) + (e - 4);
                i1 = (e < 4) ? SL(c1) + e : 288 + SL(c1) + (e - 4);
                i2 = (e < 4) ? SL(c2) + e : 288 + SL(c2) + (e - 4);
                i3 = (e < 4) ? SL(c3) + e : 288 + SL(c3) + (e - 4);
            }
            const float* sp = scr + r * 576;
            float gi = bD[j], gf = bD[j + 128], gg = bD[j + 256], go = bD[j + 384];
            #pragma unroll
            for (int ks = 0; ks < 8; ++ks) {
                const float* p = sp + ks * 1152;
                gi += p[i0]; gf += p[i1]; gg += p[i2]; go += p[i3];
            }
            float c = sigm(gf) * hc2[r][H_ + j] + sigm(gi) * tanh_fast(gg);
            float h = sigm(go) * tanh_fast(c);
            hc2[r][H_ + j] = c; hc2[r][j] = h;
        }
        __syncthreads();

        // P6: output dot (no trailing barrier needed)
        if (tid < 128) {
            int r = tid >> 6, lane = tid & 63;
            float v = hc2[r][lane] * rw[lane] + hc2[r][lane + 64] * rw[lane + 64];
            for (int off = 32; off > 0; off >>= 1) v += __shfl_xor(v, off, 64);
            if (lane == 0) out[(b0 + r) * TD + td] = v + rb;
        }
    }
}

extern "C" void kernel_launch(void* const* d_in, const int* in_sizes, int n_in,
                              void* d_out, int out_size, void* d_ws, size_t ws_size,
                              hipStream_t stream)
{
    (void)in_sizes; (void)n_in; (void)out_size;
    if (ws_size < (size_t)WS_FLOATS * sizeof(float)) return;

    const float* x_all = (const float*)d_in[0];
    const float* Wi_b  = (const float*)d_in[3];
    const float* Vd_b  = (const float*)d_in[6];
    const float* Wx_b  = (const float*)d_in[16];
    const float* V_w   = (const float*)d_in[18];
    const float* V_b   = (const float*)d_in[19];
    const float* reg_w = (const float*)d_in[24];
    const float* reg_b = (const float*)d_in[25];
    float* ws  = (float*)d_ws;
    float* out = (float*)d_out;
    int* flags = (int*)d_out;   // first 64 ints of out; zeroed by prep, overwritten by dec

    PrepArgs pa{
        (const float*)d_in[4],  // We_w
        (const float*)d_in[2],  // Wi_w
        (const float*)d_in[5],  // Vd_w
        (const float*)d_in[7],  // enc_Wih
        (const float*)d_in[8],  // enc_Whh
        (const float*)d_in[9],  // enc_bih
        (const float*)d_in[10], // enc_bhh
        (const float*)d_in[11], // mid_Wih
        (const float*)d_in[12], // mid_Whh
        (const float*)d_in[13], // mid_bih
        (const float*)d_in[14], // mid_bhh
        (const float*)d_in[15], // Wx_w
        (const float*)d_in[17], // Wh_w
        (const float*)d_in[20], // dec_Wih
        (const float*)d_in[21], // dec_Whh
        (const float*)d_in[22], // dec_bih
        (const float*)d_in[23]  // dec_bhh
    };

    prep_kernel<<<56, 256, 0, stream>>>(pa, ws, flags);
    enc_mid_kernel<<<128, 512, 0, stream>>>(x_all, Wi_b, Vd_b, Wx_b, ws, flags);
    dec_kernel<<<512, 512, 0, stream>>>(V_w, V_b, reg_w, reg_b, ws, out);
}